// Round 3
// baseline (1089.039 us; speedup 1.0000x reference)
//
#include <hip/hip_runtime.h>
#include <hip/hip_bf16.h>
#include <stdint.h>

#define BT   16384   // B*T
#define TT   4096    // T
#define NB   4       // B
#define DD   1024
#define RR   128
#define DFFC 4096

typedef __bf16 bf16_8 __attribute__((ext_vector_type(8)));
typedef float  f32x4  __attribute__((ext_vector_type(4)));

__device__ __forceinline__ void async16(const void* g, void* l) {
  __builtin_amdgcn_global_load_lds((__attribute__((address_space(1))) void*)(g),
                                   (__attribute__((address_space(3))) void*)(l),
                                   16, 0, 0);
}

// ---------------- fp32 -> bf16 convert ----------------
__global__ __launch_bounds__(256) void cvt_k(const float* __restrict__ src,
                                             __hip_bfloat16* __restrict__ dst, int n4) {
  const int i = blockIdx.x * 256 + threadIdx.x;
  if (i >= n4) return;
  const float4 v = ((const float4*)src)[i];
  __hip_bfloat16* o = dst + (size_t)i * 4;
  o[0] = __float2bfloat16(v.x);
  o[1] = __float2bfloat16(v.y);
  o[2] = __float2bfloat16(v.z);
  o[3] = __float2bfloat16(v.w);
}

// ---------------- RMSNorm (fp32 in, bf16 out) ----------------
__global__ __launch_bounds__(256) void rmsnorm_k(const float* __restrict__ x,
                                                 const float* __restrict__ wgt,
                                                 __hip_bfloat16* __restrict__ out) {
  const int row = blockIdx.x;
  const int t = threadIdx.x;
  const float4 v = ((const float4*)(x + (size_t)row * DD))[t];
  float ss = v.x*v.x + v.y*v.y + v.z*v.z + v.w*v.w;
  #pragma unroll
  for (int m = 1; m < 64; m <<= 1) ss += __shfl_xor(ss, m, 64);
  __shared__ float red[4];
  if ((t & 63) == 0) red[t >> 6] = ss;
  __syncthreads();
  ss = red[0] + red[1] + red[2] + red[3];
  const float rms = rsqrtf(ss * (1.0f / DD) + 1e-6f);
  const float4 wv = ((const float4*)wgt)[t];
  __hip_bfloat16* o = out + (size_t)row * DD + t * 4;
  o[0] = __float2bfloat16(v.x * rms * wv.x);
  o[1] = __float2bfloat16(v.y * rms * wv.y);
  o[2] = __float2bfloat16(v.z * rms * wv.z);
  o[3] = __float2bfloat16(v.w * rms * wv.w);
}

// ---------------- RoPE: qkv (M,384) -> qr, kr (M,128) ----------------
__global__ __launch_bounds__(256) void rope_k(const __hip_bfloat16* __restrict__ qkv,
                                              const float* __restrict__ cosb,
                                              const float* __restrict__ sinb,
                                              __hip_bfloat16* __restrict__ qr,
                                              __hip_bfloat16* __restrict__ kr) {
  const int idx = blockIdx.x * 256 + threadIdx.x;  // 0 .. BT*64-1
  const int row = idx >> 6;
  const int i = idx & 63;
  const int tpos = row & (TT - 1);
  const float c = cosb[tpos * 64 + i];
  const float s = sinb[tpos * 64 + i];
  const size_t base = (size_t)row * 384;
  const float q1 = __bfloat162float(qkv[base + i]);
  const float q2 = __bfloat162float(qkv[base + 64 + i]);
  const float k1 = __bfloat162float(qkv[base + 128 + i]);
  const float k2 = __bfloat162float(qkv[base + 192 + i]);
  const size_t ob = (size_t)row * 128;
  qr[ob + i]      = __float2bfloat16( q1 * c + q2 * s);
  qr[ob + 64 + i] = __float2bfloat16(-q1 * s + q2 * c);
  kr[ob + i]      = __float2bfloat16( k1 * c + k2 * s);
  kr[ob + 64 + i] = __float2bfloat16(-k1 * s + k2 * c);
}

// ---------------- V transpose: qkv v-cols -> Vt (B,128,T) ----------------
__global__ __launch_bounds__(256) void vtrans_k(const __hip_bfloat16* __restrict__ qkv,
                                                __hip_bfloat16* __restrict__ Vt) {
  const int b = blockIdx.y, t0 = blockIdx.x * 64, t = threadIdx.x;
  #pragma unroll
  for (int i = 0; i < 4; ++i) {
    const int flat8 = i * 256 + t;       // 0..1023
    const int row = flat8 >> 4;          // 0..63  (t-local)
    const int d8 = (flat8 & 15) * 8;     // dim start
    const bf16_8 v = *(const bf16_8*)&qkv[((size_t)(b * TT + t0 + row)) * 384 + 256 + d8];
    #pragma unroll
    for (int j = 0; j < 8; ++j)
      ((__bf16*)Vt)[((size_t)(b * 128 + d8 + j)) * TT + t0 + row] = v[j];
  }
}

// ======== XOR-swizzled LDS tiles (period-4 for 32-elem rows) ========
// LDS slot (row, p) holds global chunk p ^ (row & 3); staging permutes the
// per-lane GLOBAL address (LDS dest of global_load_lds is fixed lane*16).
// Read address for global chunk `quad` of row r: position quad ^ (r & 3).
// This turns the 8-way read bank conflict into 2-way (free, m136).

// ---------------- GEMM: C(M,N) = A(M,K) @ Bw(N,K)^T, bf16 MFMA ----------------
enum { EPI_BF16 = 0, EPI_RESID = 1, EPI_GATE = 2 };

template <int EPI>
__global__ __launch_bounds__(256) void gemm_bt(
    const __hip_bfloat16* __restrict__ A,
    const __hip_bfloat16* __restrict__ Bw,
    const float* __restrict__ resid,
    const __hip_bfloat16* __restrict__ gate,
    __hip_bfloat16* __restrict__ outb,
    float* __restrict__ outf,
    int N, int K) {
  __shared__ __hip_bfloat16 As[128 * 32];
  __shared__ __hip_bfloat16 Bs[128 * 32];
  const int t = threadIdx.x;
  const int w = t >> 6, lane = t & 63;
  const int wm = w >> 1, wn = w & 1;
  const int quad = lane >> 4, l16 = lane & 15;
  const int m0 = blockIdx.y * 128, n0 = blockIdx.x * 128;

  const __hip_bfloat16* Ab = A + (size_t)m0 * K;
  const __hip_bfloat16* Bb = Bw + (size_t)n0 * K;

  const int r0 = w * 16 + (lane >> 2);               // staged row (issue 0)
  const int r1 = r0 + 64;                            // issue 1 (same row&3)
  const int c0 = (((lane & 3) ^ ((lane >> 2) & 3)) << 3);  // swizzled chunk
  __hip_bfloat16* lA0 = &As[w * 512];
  __hip_bfloat16* lA1 = &As[2048 + w * 512];
  __hip_bfloat16* lB0 = &Bs[w * 512];
  __hip_bfloat16* lB1 = &Bs[2048 + w * 512];

  const int sc = ((quad ^ (l16 & 3)) << 3);          // swizzled read col

  f32x4 acc[4][4] = {};

  for (int k0 = 0; k0 < K; k0 += 32) {
    async16(Ab + (size_t)r0 * K + k0 + c0, lA0);
    async16(Ab + (size_t)r1 * K + k0 + c0, lA1);
    async16(Bb + (size_t)r0 * K + k0 + c0, lB0);
    async16(Bb + (size_t)r1 * K + k0 + c0, lB1);
    __syncthreads();
    bf16_8 af[4], bfr[4];
    #pragma unroll
    for (int i = 0; i < 4; ++i) {
      af[i]  = *(const bf16_8*)&As[(wm * 64 + i * 16 + l16) * 32 + sc];
      bfr[i] = *(const bf16_8*)&Bs[(wn * 64 + i * 16 + l16) * 32 + sc];
    }
    #pragma unroll
    for (int mt = 0; mt < 4; ++mt) {
      #pragma unroll
      for (int nt = 0; nt < 4; ++nt)
        acc[mt][nt] = __builtin_amdgcn_mfma_f32_16x16x32_bf16(af[mt], bfr[nt], acc[mt][nt], 0, 0, 0);
    }
    __syncthreads();
  }

  #pragma unroll
  for (int mt = 0; mt < 4; ++mt) {
    #pragma unroll
    for (int nt = 0; nt < 4; ++nt) {
      #pragma unroll
      for (int r = 0; r < 4; ++r) {
        const int row = m0 + wm * 64 + mt * 16 + quad * 4 + r;
        const int col = n0 + wn * 64 + nt * 16 + l16;
        const size_t idx = (size_t)row * N + col;
        const float v = acc[mt][nt][r];
        if (EPI == EPI_BF16) {
          outb[idx] = __float2bfloat16(v);
        } else if (EPI == EPI_RESID) {
          // resid may alias outf; same-thread same-idx read->write is data-dep safe
          outf[idx] = resid[idx] + v;
        } else {
          const float sv = v / (1.0f + __expf(-v));
          outb[idx] = __float2bfloat16(__bfloat162float(gate[idx]) * sv);
        }
      }
    }
  }
}

// ---------------- fused FFN up: g = (A@B1^T) * silu(A@B3^T) ----------------
// A (M,1024), B1/B3 (4096,1024), out g (M,4096) bf16. 128x128 tile, stage A
// once + both B tiles: 32 MFMA per staging round (2x ratio of gemm_bt).
__global__ __launch_bounds__(256) void gemm_w13(
    const __hip_bfloat16* __restrict__ A,
    const __hip_bfloat16* __restrict__ B1,
    const __hip_bfloat16* __restrict__ B3,
    __hip_bfloat16* __restrict__ outg) {
  constexpr int K = 1024;
  __shared__ __hip_bfloat16 As[128 * 32];
  __shared__ __hip_bfloat16 B1s[128 * 32];
  __shared__ __hip_bfloat16 B3s[128 * 32];
  const int t = threadIdx.x;
  const int w = t >> 6, lane = t & 63;
  const int wm = w >> 1, wn = w & 1;
  const int quad = lane >> 4, l16 = lane & 15;
  const int m0 = blockIdx.y * 128, n0 = blockIdx.x * 128;

  const __hip_bfloat16* Ab  = A  + (size_t)m0 * K;
  const __hip_bfloat16* B1b = B1 + (size_t)n0 * K;
  const __hip_bfloat16* B3b = B3 + (size_t)n0 * K;

  const int r0 = w * 16 + (lane >> 2);
  const int r1 = r0 + 64;
  const int c0 = (((lane & 3) ^ ((lane >> 2) & 3)) << 3);
  const int sc = ((quad ^ (l16 & 3)) << 3);

  f32x4 acc1[4][4] = {};
  f32x4 acc3[4][4] = {};

  for (int k0 = 0; k0 < K; k0 += 32) {
    async16(Ab  + (size_t)r0 * K + k0 + c0, &As[w * 512]);
    async16(Ab  + (size_t)r1 * K + k0 + c0, &As[2048 + w * 512]);
    async16(B1b + (size_t)r0 * K + k0 + c0, &B1s[w * 512]);
    async16(B1b + (size_t)r1 * K + k0 + c0, &B1s[2048 + w * 512]);
    async16(B3b + (size_t)r0 * K + k0 + c0, &B3s[w * 512]);
    async16(B3b + (size_t)r1 * K + k0 + c0, &B3s[2048 + w * 512]);
    __syncthreads();
    bf16_8 af[4], b1f[4], b3f[4];
    #pragma unroll
    for (int i = 0; i < 4; ++i) {
      af[i]  = *(const bf16_8*)&As[(wm * 64 + i * 16 + l16) * 32 + sc];
      b1f[i] = *(const bf16_8*)&B1s[(wn * 64 + i * 16 + l16) * 32 + sc];
      b3f[i] = *(const bf16_8*)&B3s[(wn * 64 + i * 16 + l16) * 32 + sc];
    }
    #pragma unroll
    for (int mt = 0; mt < 4; ++mt) {
      #pragma unroll
      for (int nt = 0; nt < 4; ++nt) {
        acc1[mt][nt] = __builtin_amdgcn_mfma_f32_16x16x32_bf16(af[mt], b1f[nt], acc1[mt][nt], 0, 0, 0);
        acc3[mt][nt] = __builtin_amdgcn_mfma_f32_16x16x32_bf16(af[mt], b3f[nt], acc3[mt][nt], 0, 0, 0);
      }
    }
    __syncthreads();
  }

  #pragma unroll
  for (int mt = 0; mt < 4; ++mt) {
    #pragma unroll
    for (int nt = 0; nt < 4; ++nt) {
      #pragma unroll
      for (int r = 0; r < 4; ++r) {
        const int row = m0 + wm * 64 + mt * 16 + quad * 4 + r;
        const int col = n0 + wn * 64 + nt * 16 + l16;
        const float v1 = acc1[mt][nt][r];
        const float v3 = acc3[mt][nt][r];
        const float sv = v3 / (1.0f + __expf(-v3));
        outg[(size_t)row * DFFC + col] = __float2bfloat16(v1 * sv);
      }
    }
  }
}

// ---------------- sliding-window flash attention ----------------
// grid (T/64, B); 256 threads; wave w owns q rows [t0+16w, t0+16w+16)
// Ksm swizzle period 16 (128-elem rows), Vsm period 8 (64-elem rows),
// Psm padded to stride 72 (VALU-written, padding allowed).
__global__ __launch_bounds__(256) void attn_k(const __hip_bfloat16* __restrict__ qr,
                                              const __hip_bfloat16* __restrict__ kr,
                                              const __hip_bfloat16* __restrict__ Vt,
                                              __hip_bfloat16* __restrict__ y,
                                              const int* __restrict__ winp) {
  __shared__ __hip_bfloat16 Ksm[64 * 128];   // key-major, swizzled
  __shared__ __hip_bfloat16 Vsm[128 * 64];   // dim-major, swizzled
  __shared__ __hip_bfloat16 Psm[4 * 16 * 72];
  const int t = threadIdx.x, w = t >> 6, lane = t & 63;
  const int quad = lane >> 4, l16 = lane & 15;
  const int b = blockIdx.y, t0 = blockIdx.x * 64;
  const int tw0 = t0 + w * 16;
  const int win = *winp;
  int kb_lo = t0 - win;
  if (kb_lo < 0) kb_lo = 0;
  kb_lo &= ~63;

  bf16_8 qf[4];
  const __hip_bfloat16* qb = qr + ((size_t)(b * TT + tw0 + l16)) * 128 + quad * 8;
  #pragma unroll
  for (int kk = 0; kk < 4; ++kk) qf[kk] = *(const bf16_8*)(qb + kk * 32);

  f32x4 o[8] = {};
  float mrow[4] = {-1e30f, -1e30f, -1e30f, -1e30f};
  float lrow[4] = {0.f, 0.f, 0.f, 0.f};
  const float scale = 0.08838834764831845f;  // 1/sqrt(128)

  // per-lane swizzled staging offsets
  const int krow_loc = (w * 4) + (lane >> 4);          // row within 16-row issue grp
  const int kc = ((lane & 15) ^ (krow_loc & 15)) << 3; // K chunk (elements)
  const int vloc = lane >> 3;                          // row within 8-row issue grp
  const int vc = ((lane & 7) ^ vloc) << 3;             // V chunk (elements)

  for (int kb0 = kb_lo; kb0 <= t0; kb0 += 64) {
    const __hip_bfloat16* kbp = kr + ((size_t)(b * TT + kb0)) * 128;
    #pragma unroll
    for (int i = 0; i < 4; ++i) {
      const int krow = i * 16 + krow_loc;
      async16(kbp + (size_t)krow * 128 + kc, &Ksm[i * 2048 + w * 512]);
    }
    #pragma unroll
    for (int i = 0; i < 4; ++i) {
      const int d0 = (i * 4 + w) * 8;
      const int dr = d0 + vloc;
      async16(Vt + ((size_t)(b * 128 + dr)) * TT + kb0 + vc, &Vsm[d0 * 64]);
    }
    __syncthreads();

    // S = Q K^T   (K read: chunk kk*4+quad at swizzled position ^ l16)
    f32x4 s[4] = {};
    #pragma unroll
    for (int kk = 0; kk < 4; ++kk) {
      #pragma unroll
      for (int nt = 0; nt < 4; ++nt) {
        const int cc = ((kk * 4 + quad) ^ l16) << 3;
        const bf16_8 bfrag = *(const bf16_8*)&Ksm[(nt * 16 + l16) * 128 + cc];
        s[nt] = __builtin_amdgcn_mfma_f32_16x16x32_bf16(qf[kk], bfrag, s[nt], 0, 0, 0);
      }
    }

    // mask + per-row block max
    float mb[4] = {-1e30f, -1e30f, -1e30f, -1e30f};
    #pragma unroll
    for (int nt = 0; nt < 4; ++nt) {
      #pragma unroll
      for (int r = 0; r < 4; ++r) {
        const int tq = tw0 + quad * 4 + r;
        const int scol = kb0 + nt * 16 + l16;
        float v = s[nt][r] * scale;
        const bool ok = (scol <= tq) && (tq - scol <= win);
        v = ok ? v : -1e30f;
        s[nt][r] = v;
        mb[r] = fmaxf(mb[r], v);
      }
    }

    // online softmax update (16-lane groups share a quad -> share rows)
    #pragma unroll
    for (int r = 0; r < 4; ++r) {
      float m = mb[r];
      m = fmaxf(m, __shfl_xor(m, 1, 16));
      m = fmaxf(m, __shfl_xor(m, 2, 16));
      m = fmaxf(m, __shfl_xor(m, 4, 16));
      m = fmaxf(m, __shfl_xor(m, 8, 16));
      const float mn = fmaxf(mrow[r], m);
      const float alpha = __expf(mrow[r] - mn);
      mrow[r] = mn;
      float rs = 0.f;
      #pragma unroll
      for (int nt = 0; nt < 4; ++nt) {
        const float pv = __expf(s[nt][r] - mn);
        s[nt][r] = pv;
        rs += pv;
      }
      rs += __shfl_xor(rs, 1, 16);
      rs += __shfl_xor(rs, 2, 16);
      rs += __shfl_xor(rs, 4, 16);
      rs += __shfl_xor(rs, 8, 16);
      lrow[r] = lrow[r] * alpha + rs;
      #pragma unroll
      for (int n2 = 0; n2 < 8; ++n2) o[n2][r] *= alpha;
    }

    // P: C-layout -> LDS (A-layout read), stride-72 pad
    __hip_bfloat16* pw = &Psm[w * 1152];
    #pragma unroll
    for (int nt = 0; nt < 4; ++nt) {
      #pragma unroll
      for (int r = 0; r < 4; ++r)
        pw[(quad * 4 + r) * 72 + nt * 16 + l16] = __float2bfloat16(s[nt][r]);
    }
    asm volatile("s_waitcnt lgkmcnt(0)" ::: "memory");

    // O += P V   (V read: chunk kk2*4+quad at swizzled position ^ (l16&7))
    #pragma unroll
    for (int kk2 = 0; kk2 < 2; ++kk2) {
      const bf16_8 pa = *(const bf16_8*)&Psm[w * 1152 + l16 * 72 + kk2 * 32 + quad * 8];
      #pragma unroll
      for (int n2 = 0; n2 < 8; ++n2) {
        const int cc = ((kk2 * 4 + quad) ^ (l16 & 7)) << 3;
        const bf16_8 vb = *(const bf16_8*)&Vsm[(n2 * 16 + l16) * 64 + cc];
        o[n2] = __builtin_amdgcn_mfma_f32_16x16x32_bf16(pa, vb, o[n2], 0, 0, 0);
      }
    }
    __syncthreads();
  }

  #pragma unroll
  for (int n2 = 0; n2 < 8; ++n2) {
    #pragma unroll
    for (int r = 0; r < 4; ++r) {
      const int row = b * TT + tw0 + quad * 4 + r;
      const int col = n2 * 16 + l16;
      y[(size_t)row * 128 + col] = __float2bfloat16(o[n2][r] / lrow[r]);
    }
  }
}

// ---------------- launch ----------------
extern "C" void kernel_launch(void* const* d_in, const int* in_sizes, int n_in,
                              void* d_out, int out_size, void* d_ws, size_t ws_size,
                              hipStream_t stream) {
  const float* x    = (const float*)d_in[0];
  const float* Uq   = (const float*)d_in[1];
  const float* Uk   = (const float*)d_in[2];
  const float* Uv   = (const float*)d_in[3];
  const float* cosb = (const float*)d_in[4];
  const float* sinb = (const float*)d_in[5];
  const float* ln1  = (const float*)d_in[6];
  const float* ln2  = (const float*)d_in[7];
  const float* Wo   = (const float*)d_in[8];
  const float* w1   = (const float*)d_in[9];
  const float* w3   = (const float*)d_in[10];
  const float* w2   = (const float*)d_in[11];
  const int*   winp = (const int*)d_in[12];
  float* out = (float*)d_out;

  uint8_t* p = (uint8_t*)d_ws;
  auto take = [&](size_t bytes) {
    uint8_t* q = p;
    p += (bytes + 255) & ~(size_t)255;
    return q;
  };

  __hip_bfloat16* gb     = (__hip_bfloat16*)take((size_t)BT * DFFC * 2);  // 128 MB
  __hip_bfloat16* normed = (__hip_bfloat16*)take((size_t)BT * DD * 2);    // 32 MB
  __hip_bfloat16* hb     = normed;   // aliased: normed dead after qkv gemm
  __hip_bfloat16* qkv    = (__hip_bfloat16*)take((size_t)BT * 384 * 2);   // 12 MB
  __hip_bfloat16* yb     = qkv;      // aliased: qkv dead after rope+vtrans
  __hip_bfloat16* qr_    = (__hip_bfloat16*)take((size_t)BT * RR * 2);    // 4 MB
  __hip_bfloat16* kr_    = (__hip_bfloat16*)take((size_t)BT * RR * 2);    // 4 MB
  __hip_bfloat16* Vt     = (__hip_bfloat16*)take((size_t)BT * RR * 2);    // 4 MB
  __hip_bfloat16* Ucat   = (__hip_bfloat16*)take((size_t)384 * DD * 2);
  __hip_bfloat16* Wob    = (__hip_bfloat16*)take((size_t)DD * RR * 2);
  __hip_bfloat16* W1b    = (__hip_bfloat16*)take((size_t)DFFC * DD * 2);
  __hip_bfloat16* W3b    = (__hip_bfloat16*)take((size_t)DFFC * DD * 2);
  __hip_bfloat16* W2b    = (__hip_bfloat16*)take((size_t)DD * DFFC * 2);
  float* x_mid = out;  // x_mid lives in d_out (fp32); resid alias is data-dep safe

  // weight converts
  cvt_k<<<128, 256, 0, stream>>>(Uq, Ucat, RR * DD / 4);
  cvt_k<<<128, 256, 0, stream>>>(Uk, Ucat + (size_t)RR * DD, RR * DD / 4);
  cvt_k<<<128, 256, 0, stream>>>(Uv, Ucat + (size_t)2 * RR * DD, RR * DD / 4);
  cvt_k<<<128, 256, 0, stream>>>(Wo, Wob, DD * RR / 4);
  cvt_k<<<4096, 256, 0, stream>>>(w1, W1b, DFFC * DD / 4);
  cvt_k<<<4096, 256, 0, stream>>>(w3, W3b, DFFC * DD / 4);
  cvt_k<<<4096, 256, 0, stream>>>(w2, W2b, DD * DFFC / 4);

  // rmsnorm1
  rmsnorm_k<<<BT, 256, 0, stream>>>(x, ln1, normed);

  // qkv = normed @ Ucat^T   (M=16384, N=384, K=1024)
  gemm_bt<EPI_BF16><<<dim3(3, 128), 256, 0, stream>>>(normed, Ucat, nullptr, nullptr,
                                                      qkv, nullptr, 384, DD);

  // rope q,k ; transpose v
  rope_k<<<BT * 64 / 256, 256, 0, stream>>>(qkv, cosb, sinb, qr_, kr_);
  vtrans_k<<<dim3(TT / 64, NB), 256, 0, stream>>>(qkv, Vt);

  // attention (writes yb over the dead qkv region)
  attn_k<<<dim3(TT / 64, NB), 256, 0, stream>>>(qr_, kr_, Vt, yb, winp);

  // x_mid = x + y @ Wo^T   (N=1024, K=128)  -> d_out
  gemm_bt<EPI_RESID><<<dim3(8, 128), 256, 0, stream>>>(yb, Wob, x, nullptr,
                                                       nullptr, x_mid, DD, RR);

  // rmsnorm2 (reads d_out, writes hb over dead normed)
  rmsnorm_k<<<BT, 256, 0, stream>>>(x_mid, ln2, hb);

  // g = (h @ w1^T) * silu(h @ w3^T)   fused, N=4096, K=1024
  gemm_w13<<<dim3(32, 128), 256, 0, stream>>>(hb, W1b, W3b, gb);

  // out = x_mid + g @ w2^T  (N=1024, K=4096; resid aliases outf, data-dep safe)
  gemm_bt<EPI_RESID><<<dim3(8, 128), 256, 0, stream>>>(gb, W2b, x_mid, nullptr,
                                                       nullptr, out, DD, DFFC);
}

// Round 4
// 875.694 us; speedup vs baseline: 1.2436x; 1.2436x over previous
//
#include <hip/hip_runtime.h>
#include <hip/hip_bf16.h>
#include <stdint.h>

#define BT   16384   // B*T
#define TT   4096    // T
#define NB   4       // B
#define DD   1024
#define RR   128
#define DFFC 4096

typedef __bf16 bf16_8 __attribute__((ext_vector_type(8)));
typedef float  f32x4  __attribute__((ext_vector_type(4)));

__device__ __forceinline__ void async16(const void* g, void* l) {
  __builtin_amdgcn_global_load_lds((__attribute__((address_space(1))) void*)(g),
                                   (__attribute__((address_space(3))) void*)(l),
                                   16, 0, 0);
}

// ---------------- fp32 -> bf16 convert ----------------
__global__ __launch_bounds__(256) void cvt_k(const float* __restrict__ src,
                                             __hip_bfloat16* __restrict__ dst, int n4) {
  const int i = blockIdx.x * 256 + threadIdx.x;
  if (i >= n4) return;
  const float4 v = ((const float4*)src)[i];
  __hip_bfloat16* o = dst + (size_t)i * 4;
  o[0] = __float2bfloat16(v.x);
  o[1] = __float2bfloat16(v.y);
  o[2] = __float2bfloat16(v.z);
  o[3] = __float2bfloat16(v.w);
}

// ---------------- RMSNorm (fp32 in, bf16 out) ----------------
__global__ __launch_bounds__(256) void rmsnorm_k(const float* __restrict__ x,
                                                 const float* __restrict__ wgt,
                                                 __hip_bfloat16* __restrict__ out) {
  const int row = blockIdx.x;
  const int t = threadIdx.x;
  const float4 v = ((const float4*)(x + (size_t)row * DD))[t];
  float ss = v.x*v.x + v.y*v.y + v.z*v.z + v.w*v.w;
  #pragma unroll
  for (int m = 1; m < 64; m <<= 1) ss += __shfl_xor(ss, m, 64);
  __shared__ float red[4];
  if ((t & 63) == 0) red[t >> 6] = ss;
  __syncthreads();
  ss = red[0] + red[1] + red[2] + red[3];
  const float rms = rsqrtf(ss * (1.0f / DD) + 1e-6f);
  const float4 wv = ((const float4*)wgt)[t];
  __hip_bfloat16* o = out + (size_t)row * DD + t * 4;
  o[0] = __float2bfloat16(v.x * rms * wv.x);
  o[1] = __float2bfloat16(v.y * rms * wv.y);
  o[2] = __float2bfloat16(v.z * rms * wv.z);
  o[3] = __float2bfloat16(v.w * rms * wv.w);
}

// ---------------- RoPE: qkv (M,384) -> qr, kr (M,128) ----------------
__global__ __launch_bounds__(256) void rope_k(const __hip_bfloat16* __restrict__ qkv,
                                              const float* __restrict__ cosb,
                                              const float* __restrict__ sinb,
                                              __hip_bfloat16* __restrict__ qr,
                                              __hip_bfloat16* __restrict__ kr) {
  const int idx = blockIdx.x * 256 + threadIdx.x;  // 0 .. BT*64-1
  const int row = idx >> 6;
  const int i = idx & 63;
  const int tpos = row & (TT - 1);
  const float c = cosb[tpos * 64 + i];
  const float s = sinb[tpos * 64 + i];
  const size_t base = (size_t)row * 384;
  const float q1 = __bfloat162float(qkv[base + i]);
  const float q2 = __bfloat162float(qkv[base + 64 + i]);
  const float k1 = __bfloat162float(qkv[base + 128 + i]);
  const float k2 = __bfloat162float(qkv[base + 192 + i]);
  const size_t ob = (size_t)row * 128;
  qr[ob + i]      = __float2bfloat16( q1 * c + q2 * s);
  qr[ob + 64 + i] = __float2bfloat16(-q1 * s + q2 * c);
  kr[ob + i]      = __float2bfloat16( k1 * c + k2 * s);
  kr[ob + 64 + i] = __float2bfloat16(-k1 * s + k2 * c);
}

// ---------------- V transpose: qkv v-cols -> Vt (B,128,T) ----------------
__global__ __launch_bounds__(256) void vtrans_k(const __hip_bfloat16* __restrict__ qkv,
                                                __hip_bfloat16* __restrict__ Vt) {
  const int b = blockIdx.y, t0 = blockIdx.x * 64, t = threadIdx.x;
  #pragma unroll
  for (int i = 0; i < 4; ++i) {
    const int flat8 = i * 256 + t;       // 0..1023
    const int row = flat8 >> 4;          // 0..63  (t-local)
    const int d8 = (flat8 & 15) * 8;     // dim start
    const bf16_8 v = *(const bf16_8*)&qkv[((size_t)(b * TT + t0 + row)) * 384 + 256 + d8];
    #pragma unroll
    for (int j = 0; j < 8; ++j)
      ((__bf16*)Vt)[((size_t)(b * 128 + d8 + j)) * TT + t0 + row] = v[j];
  }
}

// ---------------- GEMM: C(M,N) = A(M,K) @ Bw(N,K)^T, bf16 MFMA ----------------
// BK=64 staging (16 K-iters at K=1024): 32 MFMA per barrier, 32 KB LDS.
// XOR swizzle: LDS slot (row, p) [p in 0..7, 8-elem chunks of a 64-elem row]
// holds global chunk p ^ (row & 7). Read of chunk (kc*4+quad) of row r is at
// position (kc*4+quad) ^ (r&7); colliding 16-lane sets (row stride = 128 B ==
// 0 mod 32 banks) spread over 8 positions -> 2 lanes/bank = free (m136).
enum { EPI_BF16 = 0, EPI_RESID = 1, EPI_GATE = 2 };

template <int EPI>
__global__ __launch_bounds__(256) void gemm_bt(
    const __hip_bfloat16* __restrict__ A,
    const __hip_bfloat16* __restrict__ Bw,
    const float* __restrict__ resid,
    const __hip_bfloat16* __restrict__ gate,
    __hip_bfloat16* __restrict__ outb,
    float* __restrict__ outf,
    int N, int K) {
  __shared__ __hip_bfloat16 As[128 * 64];
  __shared__ __hip_bfloat16 Bs[128 * 64];
  const int t = threadIdx.x;
  const int w = t >> 6, lane = t & 63;
  const int wm = w >> 1, wn = w & 1;
  const int quad = lane >> 4, l16 = lane & 15;
  const int m0 = blockIdx.y * 128, n0 = blockIdx.x * 128;

  const __hip_bfloat16* Ab = A + (size_t)m0 * K;
  const __hip_bfloat16* Bb = Bw + (size_t)n0 * K;

  // staging: issue j covers rows [j*32, j*32+32); this thread's row/col
  const int rloc = w * 8 + (lane >> 3);                  // 0..31 within issue
  const int c0 = (((lane & 7) ^ ((lane >> 3) & 7)) << 3);  // swizzled col chunk
  const int swz = (l16 & 7);                             // read-side row key

  f32x4 acc[4][4] = {};

  for (int k0 = 0; k0 < K; k0 += 64) {
    #pragma unroll
    for (int j = 0; j < 4; ++j) {
      async16(Ab + (size_t)(j * 32 + rloc) * K + k0 + c0, &As[j * 2048 + w * 512]);
      async16(Bb + (size_t)(j * 32 + rloc) * K + k0 + c0, &Bs[j * 2048 + w * 512]);
    }
    __syncthreads();
    #pragma unroll
    for (int kc = 0; kc < 2; ++kc) {
      bf16_8 af[4], bfr[4];
      #pragma unroll
      for (int i = 0; i < 4; ++i) {
        const int pos = (((kc * 4 + quad) ^ swz) << 3);
        af[i]  = *(const bf16_8*)&As[(wm * 64 + i * 16 + l16) * 64 + pos];
        bfr[i] = *(const bf16_8*)&Bs[(wn * 64 + i * 16 + l16) * 64 + pos];
      }
      #pragma unroll
      for (int mt = 0; mt < 4; ++mt) {
        #pragma unroll
        for (int nt = 0; nt < 4; ++nt)
          acc[mt][nt] = __builtin_amdgcn_mfma_f32_16x16x32_bf16(af[mt], bfr[nt], acc[mt][nt], 0, 0, 0);
      }
    }
    __syncthreads();
  }

  #pragma unroll
  for (int mt = 0; mt < 4; ++mt) {
    #pragma unroll
    for (int nt = 0; nt < 4; ++nt) {
      #pragma unroll
      for (int r = 0; r < 4; ++r) {
        const int row = m0 + wm * 64 + mt * 16 + quad * 4 + r;
        const int col = n0 + wn * 64 + nt * 16 + l16;
        const size_t idx = (size_t)row * N + col;
        const float v = acc[mt][nt][r];
        if (EPI == EPI_BF16) {
          outb[idx] = __float2bfloat16(v);
        } else if (EPI == EPI_RESID) {
          // resid may alias outf; same-thread same-idx read->write is data-dep safe
          outf[idx] = resid[idx] + v;
        } else {
          const float sv = v / (1.0f + __expf(-v));
          outb[idx] = __float2bfloat16(__bfloat162float(gate[idx]) * sv);
        }
      }
    }
  }
}

// ---------------- sliding-window flash attention ----------------
// grid (T/64, B); 256 threads; wave w owns q rows [t0+16w, t0+16w+16)
// Ksm swizzle period 16 (128-elem rows), Vsm period 8 (64-elem rows),
// Psm padded to stride 72 (VALU-written, padding allowed).
__global__ __launch_bounds__(256) void attn_k(const __hip_bfloat16* __restrict__ qr,
                                              const __hip_bfloat16* __restrict__ kr,
                                              const __hip_bfloat16* __restrict__ Vt,
                                              __hip_bfloat16* __restrict__ y,
                                              const int* __restrict__ winp) {
  __shared__ __hip_bfloat16 Ksm[64 * 128];   // key-major, swizzled
  __shared__ __hip_bfloat16 Vsm[128 * 64];   // dim-major, swizzled
  __shared__ __hip_bfloat16 Psm[4 * 16 * 72];
  const int t = threadIdx.x, w = t >> 6, lane = t & 63;
  const int quad = lane >> 4, l16 = lane & 15;
  const int b = blockIdx.y, t0 = blockIdx.x * 64;
  const int tw0 = t0 + w * 16;
  const int win = *winp;
  int kb_lo = t0 - win;
  if (kb_lo < 0) kb_lo = 0;
  kb_lo &= ~63;

  bf16_8 qf[4];
  const __hip_bfloat16* qb = qr + ((size_t)(b * TT + tw0 + l16)) * 128 + quad * 8;
  #pragma unroll
  for (int kk = 0; kk < 4; ++kk) qf[kk] = *(const bf16_8*)(qb + kk * 32);

  f32x4 o[8] = {};
  float mrow[4] = {-1e30f, -1e30f, -1e30f, -1e30f};
  float lrow[4] = {0.f, 0.f, 0.f, 0.f};
  const float scale = 0.08838834764831845f;  // 1/sqrt(128)

  // per-lane swizzled staging offsets
  const int krow_loc = (w * 4) + (lane >> 4);          // row within 16-row issue grp
  const int kc = ((lane & 15) ^ (krow_loc & 15)) << 3; // K chunk (elements)
  const int vloc = lane >> 3;                          // row within 8-row issue grp
  const int vc = ((lane & 7) ^ vloc) << 3;             // V chunk (elements)

  for (int kb0 = kb_lo; kb0 <= t0; kb0 += 64) {
    const __hip_bfloat16* kbp = kr + ((size_t)(b * TT + kb0)) * 128;
    #pragma unroll
    for (int i = 0; i < 4; ++i) {
      const int krow = i * 16 + krow_loc;
      async16(kbp + (size_t)krow * 128 + kc, &Ksm[i * 2048 + w * 512]);
    }
    #pragma unroll
    for (int i = 0; i < 4; ++i) {
      const int d0 = (i * 4 + w) * 8;
      const int dr = d0 + vloc;
      async16(Vt + ((size_t)(b * 128 + dr)) * TT + kb0 + vc, &Vsm[d0 * 64]);
    }
    __syncthreads();

    // S = Q K^T   (K read: chunk kk*4+quad at swizzled position ^ l16)
    f32x4 s[4] = {};
    #pragma unroll
    for (int kk = 0; kk < 4; ++kk) {
      #pragma unroll
      for (int nt = 0; nt < 4; ++nt) {
        const int cc = ((kk * 4 + quad) ^ l16) << 3;
        const bf16_8 bfrag = *(const bf16_8*)&Ksm[(nt * 16 + l16) * 128 + cc];
        s[nt] = __builtin_amdgcn_mfma_f32_16x16x32_bf16(qf[kk], bfrag, s[nt], 0, 0, 0);
      }
    }

    // mask + per-row block max
    float mb[4] = {-1e30f, -1e30f, -1e30f, -1e30f};
    #pragma unroll
    for (int nt = 0; nt < 4; ++nt) {
      #pragma unroll
      for (int r = 0; r < 4; ++r) {
        const int tq = tw0 + quad * 4 + r;
        const int scol = kb0 + nt * 16 + l16;
        float v = s[nt][r] * scale;
        const bool ok = (scol <= tq) && (tq - scol <= win);
        v = ok ? v : -1e30f;
        s[nt][r] = v;
        mb[r] = fmaxf(mb[r], v);
      }
    }

    // online softmax update (16-lane groups share a quad -> share rows)
    #pragma unroll
    for (int r = 0; r < 4; ++r) {
      float m = mb[r];
      m = fmaxf(m, __shfl_xor(m, 1, 16));
      m = fmaxf(m, __shfl_xor(m, 2, 16));
      m = fmaxf(m, __shfl_xor(m, 4, 16));
      m = fmaxf(m, __shfl_xor(m, 8, 16));
      const float mn = fmaxf(mrow[r], m);
      const float alpha = __expf(mrow[r] - mn);
      mrow[r] = mn;
      float rs = 0.f;
      #pragma unroll
      for (int nt = 0; nt < 4; ++nt) {
        const float pv = __expf(s[nt][r] - mn);
        s[nt][r] = pv;
        rs += pv;
      }
      rs += __shfl_xor(rs, 1, 16);
      rs += __shfl_xor(rs, 2, 16);
      rs += __shfl_xor(rs, 4, 16);
      rs += __shfl_xor(rs, 8, 16);
      lrow[r] = lrow[r] * alpha + rs;
      #pragma unroll
      for (int n2 = 0; n2 < 8; ++n2) o[n2][r] *= alpha;
    }

    // P: C-layout -> LDS (A-layout read), stride-72 pad
    __hip_bfloat16* pw = &Psm[w * 1152];
    #pragma unroll
    for (int nt = 0; nt < 4; ++nt) {
      #pragma unroll
      for (int r = 0; r < 4; ++r)
        pw[(quad * 4 + r) * 72 + nt * 16 + l16] = __float2bfloat16(s[nt][r]);
    }
    asm volatile("s_waitcnt lgkmcnt(0)" ::: "memory");

    // O += P V   (V read: chunk kk2*4+quad at swizzled position ^ (l16&7))
    #pragma unroll
    for (int kk2 = 0; kk2 < 2; ++kk2) {
      const bf16_8 pa = *(const bf16_8*)&Psm[w * 1152 + l16 * 72 + kk2 * 32 + quad * 8];
      #pragma unroll
      for (int n2 = 0; n2 < 8; ++n2) {
        const int cc = ((kk2 * 4 + quad) ^ (l16 & 7)) << 3;
        const bf16_8 vb = *(const bf16_8*)&Vsm[(n2 * 16 + l16) * 64 + cc];
        o[n2] = __builtin_amdgcn_mfma_f32_16x16x32_bf16(pa, vb, o[n2], 0, 0, 0);
      }
    }
    __syncthreads();
  }

  #pragma unroll
  for (int n2 = 0; n2 < 8; ++n2) {
    #pragma unroll
    for (int r = 0; r < 4; ++r) {
      const int row = b * TT + tw0 + quad * 4 + r;
      const int col = n2 * 16 + l16;
      y[(size_t)row * 128 + col] = __float2bfloat16(o[n2][r] / lrow[r]);
    }
  }
}

// ---------------- launch ----------------
extern "C" void kernel_launch(void* const* d_in, const int* in_sizes, int n_in,
                              void* d_out, int out_size, void* d_ws, size_t ws_size,
                              hipStream_t stream) {
  const float* x    = (const float*)d_in[0];
  const float* Uq   = (const float*)d_in[1];
  const float* Uk   = (const float*)d_in[2];
  const float* Uv   = (const float*)d_in[3];
  const float* cosb = (const float*)d_in[4];
  const float* sinb = (const float*)d_in[5];
  const float* ln1  = (const float*)d_in[6];
  const float* ln2  = (const float*)d_in[7];
  const float* Wo   = (const float*)d_in[8];
  const float* w1   = (const float*)d_in[9];
  const float* w3   = (const float*)d_in[10];
  const float* w2   = (const float*)d_in[11];
  const int*   winp = (const int*)d_in[12];
  float* out = (float*)d_out;

  uint8_t* p = (uint8_t*)d_ws;
  auto take = [&](size_t bytes) {
    uint8_t* q = p;
    p += (bytes + 255) & ~(size_t)255;
    return q;
  };

  __hip_bfloat16* h1     = (__hip_bfloat16*)take((size_t)BT * DFFC * 2);  // 128 MB
  __hip_bfloat16* gb     = h1;       // aliased: gate epilogue same-idx read->write
  __hip_bfloat16* normed = (__hip_bfloat16*)take((size_t)BT * DD * 2);    // 32 MB
  __hip_bfloat16* hb     = normed;   // aliased: normed dead after qkv gemm
  __hip_bfloat16* qkv    = (__hip_bfloat16*)take((size_t)BT * 384 * 2);   // 12 MB
  __hip_bfloat16* yb     = qkv;      // aliased: qkv dead after rope+vtrans
  __hip_bfloat16* qr_    = (__hip_bfloat16*)take((size_t)BT * RR * 2);    // 4 MB
  __hip_bfloat16* kr_    = (__hip_bfloat16*)take((size_t)BT * RR * 2);    // 4 MB
  __hip_bfloat16* Vt     = (__hip_bfloat16*)take((size_t)BT * RR * 2);    // 4 MB
  __hip_bfloat16* Ucat   = (__hip_bfloat16*)take((size_t)384 * DD * 2);
  __hip_bfloat16* Wob    = (__hip_bfloat16*)take((size_t)DD * RR * 2);
  __hip_bfloat16* W1b    = (__hip_bfloat16*)take((size_t)DFFC * DD * 2);
  __hip_bfloat16* W3b    = (__hip_bfloat16*)take((size_t)DFFC * DD * 2);
  __hip_bfloat16* W2b    = (__hip_bfloat16*)take((size_t)DD * DFFC * 2);
  float* x_mid = out;  // x_mid lives in d_out (fp32); resid alias is data-dep safe

  // weight converts
  cvt_k<<<128, 256, 0, stream>>>(Uq, Ucat, RR * DD / 4);
  cvt_k<<<128, 256, 0, stream>>>(Uk, Ucat + (size_t)RR * DD, RR * DD / 4);
  cvt_k<<<128, 256, 0, stream>>>(Uv, Ucat + (size_t)2 * RR * DD, RR * DD / 4);
  cvt_k<<<128, 256, 0, stream>>>(Wo, Wob, DD * RR / 4);
  cvt_k<<<4096, 256, 0, stream>>>(w1, W1b, DFFC * DD / 4);
  cvt_k<<<4096, 256, 0, stream>>>(w3, W3b, DFFC * DD / 4);
  cvt_k<<<4096, 256, 0, stream>>>(w2, W2b, DD * DFFC / 4);

  // rmsnorm1
  rmsnorm_k<<<BT, 256, 0, stream>>>(x, ln1, normed);

  // qkv = normed @ Ucat^T   (M=16384, N=384, K=1024)
  gemm_bt<EPI_BF16><<<dim3(3, 128), 256, 0, stream>>>(normed, Ucat, nullptr, nullptr,
                                                      qkv, nullptr, 384, DD);

  // rope q,k ; transpose v
  rope_k<<<BT * 64 / 256, 256, 0, stream>>>(qkv, cosb, sinb, qr_, kr_);
  vtrans_k<<<dim3(TT / 64, NB), 256, 0, stream>>>(qkv, Vt);

  // attention (writes yb over the dead qkv region)
  attn_k<<<dim3(TT / 64, NB), 256, 0, stream>>>(qr_, kr_, Vt, yb, winp);

  // x_mid = x + y @ Wo^T   (N=1024, K=128)  -> d_out
  gemm_bt<EPI_RESID><<<dim3(8, 128), 256, 0, stream>>>(yb, Wob, x, nullptr,
                                                       nullptr, x_mid, DD, RR);

  // rmsnorm2 (reads d_out, writes hb over dead normed)
  rmsnorm_k<<<BT, 256, 0, stream>>>(x_mid, ln2, hb);

  // h1 = h @ w1^T           (N=4096, K=1024)
  gemm_bt<EPI_BF16><<<dim3(32, 128), 256, 0, stream>>>(hb, W1b, nullptr, nullptr,
                                                       h1, nullptr, DFFC, DD);
  // g = h1 * silu(h @ w3^T)  (g aliases h1; same-idx read->write data-dep safe)
  gemm_bt<EPI_GATE><<<dim3(32, 128), 256, 0, stream>>>(hb, W3b, nullptr, h1,
                                                       gb, nullptr, DFFC, DD);
  // out = x_mid + g @ w2^T  (N=1024, K=4096; resid aliases outf, data-dep safe)
  gemm_bt<EPI_RESID><<<dim3(8, 128), 256, 0, stream>>>(gb, W2b, x_mid, nullptr,
                                                       nullptr, out, DD, DFFC);
}